// Round 13
// baseline (349.006 us; speedup 1.0000x reference)
//
#include <hip/hip_runtime.h>
#include <hip/hip_bf16.h>
#include <stdint.h>

typedef float f32x4 __attribute__((ext_vector_type(4)));
typedef short s16x8 __attribute__((ext_vector_type(8)));
typedef unsigned short u16;

__device__ __forceinline__ u16 f2bf(float f) {
  uint32_t u = __float_as_uint(f);
  u = (u + 0x7fffu + ((u >> 16) & 1u)) >> 16;
  return (u16)u;
}

__device__ __forceinline__ u16 cvt_bf(float f) {
  union { __hip_bfloat16 h; u16 u; } c;
  c.h = __float2bfloat16(f);
  return c.u;
}

// Direct global->LDS DMA, 16B per lane. LDS dest = wave-uniform base + lane*16.
#define GLDS16(gsrc, ldst)                                                    \
  __builtin_amdgcn_global_load_lds(                                           \
      (const __attribute__((address_space(1))) void*)(gsrc),                  \
      (__attribute__((address_space(3))) void*)(ldst), 16, 0, 0)

// ---------------- K0a: BN fold params
__global__ void k_params(const float* __restrict__ gamma, const float* __restrict__ beta,
                         const float* __restrict__ mean, const float* __restrict__ var,
                         float* __restrict__ bnS, float* __restrict__ bnT) {
  int i = threadIdx.x;
  if (i < 512) {
    float s = gamma[i] * rsqrtf(var[i] + 1e-5f);
    bnS[i] = s;
    bnT[i] = beta[i] - mean[i] * s;
  }
}

// ---------------- K0b: f32 -> bf16 convert
__global__ void k_convert(const float* __restrict__ in, u16* __restrict__ out, int n4) {
  int i = blockIdx.x * blockDim.x + threadIdx.x;
  if (i < n4) {
    float4 v = ((const float4*)in)[i];
    ushort4 o;
    o.x = f2bf(v.x); o.y = f2bf(v.y); o.z = f2bf(v.z); o.w = f2bf(v.w);
    ((ushort4*)out)[i] = o;
  }
}

// ---------------- K0c: border2
__global__ void k_border2(const float* __restrict__ w2, const float* __restrict__ b2,
                          const float* __restrict__ bnT, float* __restrict__ border2) {
  int o = blockIdx.x;
  int l = threadIdx.x;
  float s = 0.f;
  for (int j = 0; j < 8; ++j) {
    int c = l + 64 * j;
    s += w2[o * 512 + c] * fmaxf(bnT[c], 0.f);
  }
  for (int off = 32; off > 0; off >>= 1) s += __shfl_down(s, off, 64);
  if (l == 0) border2[o] = s + b2[o];
}

// ---------------- K1a: transpose+convert x[b][k][p] f32 -> xT[b*1024+p][k] bf16
// (r1-verified). grid: CB * 88 * 16 blocks of 256; per block: 64k x 64p tile.
__global__ __launch_bounds__(256) void k_trans(const float* __restrict__ x, u16* __restrict__ xT,
                                               int b0, int CB) {
  int id = blockIdx.x;
  int bl = id / (88 * 16);
  int rem = id - bl * 88 * 16;
  int ktile = rem >> 4;
  int ptile = rem & 15;
  __shared__ __align__(16) u16 tile[64 * 80];
  int t = threadIdx.x;
  int kl = t >> 2;
  int pb = (t & 3) * 16;
  const float* src = x + ((size_t)(b0 + bl) * 5632 + (size_t)(ktile * 64 + kl)) * 1024
                       + ptile * 64 + pb;
#pragma unroll
  for (int j = 0; j < 4; ++j) {
    float4 v = *(const float4*)(src + j * 4);
    int p = pb + j * 4;
    tile[(p + 0) * 80 + kl] = f2bf(v.x);
    tile[(p + 1) * 80 + kl] = f2bf(v.y);
    tile[(p + 2) * 80 + kl] = f2bf(v.z);
    tile[(p + 3) * 80 + kl] = f2bf(v.w);
  }
  __syncthreads();
#pragma unroll
  for (int j = 0; j < 2; ++j) {
    int q = t + j * 256;
    int pl = q >> 3, g = q & 7;
    s16x8 v = *(const s16x8*)(tile + pl * 80 + g * 8);
    *(s16x8*)(xT + (size_t)(bl * 1024 + ptile * 64 + pl) * 5632 + ktile * 64 + g * 8) = v;
  }
}

// ---------------- K1b: m97-replica GEMM on pre-transposed A.
// 128m x 128n tile, BK=32, 4 waves (2x2), SINGLE-buffered linear LDS,
// 4x global_load_lds(16B)/thread/step, plain __syncthreads (vmcnt-draining) --
// the exact structure measured at 874-912 TF on this chip.
// MODE 0: full K, BN+relu -> H bf16.  MODE 1: K-split x2 -> f32 partials P.
template <int MODE>
__global__ __launch_bounds__(256) void k_gemm1t(
    const u16* __restrict__ A, const u16* __restrict__ Bw,
    const float* __restrict__ bnS, const float* __restrict__ bnT,
    u16* __restrict__ H, float* __restrict__ P, int m_off, int nMT) {
  const int K = 5632;
  const int KS = (MODE == 1) ? 2816 : 5632;
  __shared__ __align__(16) u16 sA[4096];   // [128][32] linear: row m at byte m*64
  __shared__ __align__(16) u16 sB[4096];
  int id = blockIdx.x;
  int nInner = nMT * 4;
  int inner = (MODE == 1) ? (id % nInner) : id;
  int kh = (MODE == 1) ? (id / nInner) : 0;
  int kbase = kh * 2816;
  int li = (inner % 8) * (nInner / 8) + inner / 8;   // XCD swizzle (nInner % 8 == 0)
  int nt = li & 3;
  int mt = li >> 2;
  int t = threadIdx.x;
  int l = t & 63, w = t >> 6;
  int wm = w >> 1, wn = w & 1;

  // staging: thread t covers row t>>2 (and +64), k-granule (t&3)*8
  const u16* gA = A + (size_t)(mt * 128 + (t >> 2)) * K + kbase + (t & 3) * 8;
  const u16* gB = Bw + (size_t)(nt * 128 + (t >> 2)) * K + kbase + (t & 3) * 8;
  const size_t rstep = (size_t)64 * K;
  // wave-uniform LDS byte bases (lane l lands at base + l*16)
  char* dA0 = (char*)sA + w * 1024;
  char* dA1 = (char*)sA + 4096 + w * 1024;
  char* dB0 = (char*)sB + w * 1024;
  char* dB1 = (char*)sB + 4096 + w * 1024;

  int offA[4], offB[4];
#pragma unroll
  for (int f = 0; f < 4; ++f) {
    offA[f] = (wm * 64 + f * 16 + (l & 15)) * 64 + (l >> 4) * 16;   // bytes
    offB[f] = (wn * 64 + f * 16 + (l & 15)) * 64 + (l >> 4) * 16;
  }

  f32x4 acc[4][4] = {};

  for (int k0 = 0; k0 < KS; k0 += 32) {
    GLDS16(gA, dA0);
    GLDS16(gA + rstep, dA1);
    GLDS16(gB, dB0);
    GLDS16(gB + rstep, dB1);
    gA += 32; gB += 32;
    __syncthreads();          // drains vmcnt: LDS tiles complete
    s16x8 af[4], bf[4];
#pragma unroll
    for (int f = 0; f < 4; ++f) {
      af[f] = *(const s16x8*)((const char*)sA + offA[f]);
      bf[f] = *(const s16x8*)((const char*)sB + offB[f]);
    }
#pragma unroll
    for (int i = 0; i < 4; ++i)
#pragma unroll
      for (int j = 0; j < 4; ++j)
        acc[i][j] = __builtin_amdgcn_mfma_f32_16x16x32_bf16(af[i], bf[j], acc[i][j], 0, 0, 0);
    __syncthreads();          // all reads done before next overwrite
  }

  int mb = m_off + mt * 128 + wm * 64;
  int nbase = nt * 128 + wn * 64;
  if (MODE == 0) {
#pragma unroll
    for (int j = 0; j < 4; ++j) {
      int n_g = nbase + j * 16 + (l & 15);
      float s = bnS[n_g], tt = bnT[n_g];
#pragma unroll
      for (int i = 0; i < 4; ++i)
#pragma unroll
        for (int r = 0; r < 4; ++r) {
          int m_g = mb + i * 16 + (l >> 4) * 4 + r;
          float v = fmaxf(acc[i][j][r] * s + tt, 0.f);
          H[(size_t)m_g * 512 + n_g] = f2bf(v);
        }
    }
  } else {
    float* Pd = P + (size_t)kh * (16384ull * 512);
#pragma unroll
    for (int j = 0; j < 4; ++j) {
      int n_g = nbase + j * 16 + (l & 15);
#pragma unroll
      for (int i = 0; i < 4; ++i)
#pragma unroll
        for (int r = 0; r < 4; ++r) {
          int m_g = mb + i * 16 + (l >> 4) * 4 + r;
          Pd[(size_t)m_g * 512 + n_g] = acc[i][j][r];
        }
    }
  }
}

// ---------------- K1c: combine partials -> h = bf16(relu((P0+P1)*s + t))
__global__ __launch_bounds__(256) void k_combine(
    const float* __restrict__ P, const float* __restrict__ bnS,
    const float* __restrict__ bnT, u16* __restrict__ H) {
  int i = blockIdx.x * 256 + threadIdx.x;
  const float4 a = ((const float4*)P)[i];
  const float4 b = ((const float4*)(P + 16384ull * 512))[i];
  int n0 = (i * 4) & 511;
  float4 s = *(const float4*)(bnS + n0);
  float4 tt = *(const float4*)(bnT + n0);
  ushort4 o;
  o.x = cvt_bf(fmaxf((a.x + b.x) * s.x + tt.x, 0.f));
  o.y = cvt_bf(fmaxf((a.y + b.y) * s.y + tt.y, 0.f));
  o.z = cvt_bf(fmaxf((a.z + b.z) * s.z + tt.z, 0.f));
  o.w = cvt_bf(fmaxf((a.w + b.w) * s.w + tt.w, 0.f));
  ((ushort4*)H)[i] = o;
}

// ---------------- GEMM2: 128x128 tile, BK=32, 4 waves; epilogue acc + b2 -> f32
__global__ __launch_bounds__(256, 2) void k_gemm2(
    const u16* __restrict__ A, const u16* __restrict__ B,
    const float* __restrict__ b2, float* __restrict__ C) {
  const int K = 512;
  __shared__ __align__(16) u16 sA[4096];
  __shared__ __align__(16) u16 sB[4096];
  int nb = gridDim.x;
  int id = blockIdx.x;
  int li = (id & 7) * (nb >> 3) + (id >> 3);
  int nt = li % 3;
  int mt = li / 3;
  int t = threadIdx.x;
  int l = t & 63, w = t >> 6;
  int wm = w >> 1, wn = w & 1;

  auto swz = [](int u) { int m = u >> 2, g = u & 3; return (m * 4 + (g ^ ((m >> 1) & 3))) * 8; };
  int wo0 = swz(t), wo1 = swz(t + 256);

  const u16* gA0 = A + (size_t)(mt * 128 + (t >> 2)) * K + (t & 3) * 8;
  const u16* gA1 = gA0 + (size_t)64 * K;
  const u16* gB0 = B + (size_t)(nt * 128 + (t >> 2)) * K + (t & 3) * 8;
  const u16* gB1 = gB0 + (size_t)64 * K;

  int offA[4], offB[4];
#pragma unroll
  for (int f = 0; f < 4; ++f) {
    int g = l >> 4;
    int m = wm * 64 + f * 16 + (l & 15);
    offA[f] = (m * 4 + (g ^ ((m >> 1) & 3))) * 8;
    int n = wn * 64 + f * 16 + (l & 15);
    offB[f] = (n * 4 + (g ^ ((n >> 1) & 3))) * 8;
  }

  f32x4 acc[4][4] = {};

  s16x8 rA0 = *(const s16x8*)gA0;
  s16x8 rA1 = *(const s16x8*)gA1;
  s16x8 rB0 = *(const s16x8*)gB0;
  s16x8 rB1 = *(const s16x8*)gB1;

  for (int k0 = 0; k0 < K; k0 += 32) {
    *(s16x8*)(sA + wo0) = rA0;
    *(s16x8*)(sA + wo1) = rA1;
    *(s16x8*)(sB + wo0) = rB0;
    *(s16x8*)(sB + wo1) = rB1;
    __syncthreads();
    if (k0 + 32 < K) {
      gA0 += 32; gA1 += 32; gB0 += 32; gB1 += 32;
      rA0 = *(const s16x8*)gA0;
      rA1 = *(const s16x8*)gA1;
      rB0 = *(const s16x8*)gB0;
      rB1 = *(const s16x8*)gB1;
    }
    s16x8 af[4], bf[4];
#pragma unroll
    for (int f = 0; f < 4; ++f) {
      af[f] = *(const s16x8*)(sA + offA[f]);
      bf[f] = *(const s16x8*)(sB + offB[f]);
    }
#pragma unroll
    for (int i = 0; i < 4; ++i)
#pragma unroll
      for (int j = 0; j < 4; ++j)
        acc[i][j] = __builtin_amdgcn_mfma_f32_16x16x32_bf16(af[i], bf[j], acc[i][j], 0, 0, 0);
    __syncthreads();
  }

  int mb = mt * 128 + wm * 64;
  int nbase = nt * 128 + wn * 64;
#pragma unroll
  for (int j = 0; j < 4; ++j) {
    int n_g = nbase + j * 16 + (l & 15);
    float bias = b2[n_g];
#pragma unroll
    for (int i = 0; i < 4; ++i)
#pragma unroll
      for (int r = 0; r < 4; ++r) {
        int m_g = mb + i * 16 + (l >> 4) * 4 + r;
        C[(size_t)m_g * 384 + n_g] = acc[i][j][r] + bias;
      }
  }
}

// ---------------- K4: fused DUC + softmax + bilinear(304->256, align_corners)
__global__ __launch_bounds__(256) void k_out(const float* __restrict__ c2,
                                             const float* __restrict__ border2,
                                             float* __restrict__ out) {
  int b = blockIdx.x >> 8;
  int oy = blockIdx.x & 255;
  int ox = threadIdx.x;
  const float SCL = 303.0f / 255.0f;
  float ys = oy * SCL, xs = ox * SCL;
  int y0 = (int)ys; if (y0 > 303) y0 = 303;
  int x0 = (int)xs; if (x0 > 303) x0 = 303;
  float wy = ys - (float)y0, wx = xs - (float)x0;
  int y1 = y0 + 1; if (y1 > 303) y1 = 303;
  int x1 = x0 + 1; if (x1 > 303) x1 = 303;
  int syA[2] = {y0, y1};
  int sxA[2] = {x0, x1};
  float wyA[2] = {1.f - wy, wy};
  float wxA[2] = {1.f - wx, wx};
  float acc[6] = {0.f, 0.f, 0.f, 0.f, 0.f, 0.f};
#pragma unroll
  for (int cy = 0; cy < 2; ++cy) {
#pragma unroll
    for (int cx = 0; cx < 2; ++cx) {
      float wgt = wyA[cy] * wxA[cx];
      int sy = syA[cy], sx = sxA[cx];
      if (sy >= 256 || sx >= 256) {
        float p = wgt * (1.f / 6.f);
#pragma unroll
        for (int c = 0; c < 6; ++c) acc[c] += p;
      } else {
        int i = sy >> 3, j = sx >> 3;
        int sub = ((sy & 7) << 3) | (sx & 7);
        const float* src;
        if (i == 0 || j == 0)
          src = border2 + sub;
        else
          src = c2 + (size_t)((b << 10) + ((i - 1) << 5) + (j - 1)) * 384 + sub;
        float l0 = src[0],   l1 = src[64],  l2 = src[128];
        float l3 = src[192], l4 = src[256], l5 = src[320];
        float mx = fmaxf(fmaxf(fmaxf(l0, l1), fmaxf(l2, l3)), fmaxf(l4, l5));
        float e0 = __expf(l0 - mx), e1 = __expf(l1 - mx), e2 = __expf(l2 - mx);
        float e3 = __expf(l3 - mx), e4 = __expf(l4 - mx), e5 = __expf(l5 - mx);
        float ssum = e0 + e1 + e2 + e3 + e4 + e5;
        float r = wgt / ssum;
        acc[0] += e0 * r; acc[1] += e1 * r; acc[2] += e2 * r;
        acc[3] += e3 * r; acc[4] += e4 * r; acc[5] += e5 * r;
      }
    }
  }
  size_t base = ((size_t)b * 6) << 16;
  int pix = (oy << 8) | ox;
#pragma unroll
  for (int c = 0; c < 6; ++c) out[base + ((size_t)c << 16) + pix] = acc[c];
}

extern "C" void kernel_launch(void* const* d_in, const int* in_sizes, int n_in,
                              void* d_out, int out_size, void* d_ws, size_t ws_size,
                              hipStream_t stream) {
  const float* x     = (const float*)d_in[0];
  const float* w1    = (const float*)d_in[1];
  const float* gamma = (const float*)d_in[2];
  const float* beta  = (const float*)d_in[3];
  const float* mean  = (const float*)d_in[4];
  const float* var   = (const float*)d_in[5];
  const float* w2    = (const float*)d_in[6];
  const float* b2    = (const float*)d_in[7];
  float* out = (float*)d_out;

  char* ws = (char*)d_ws;
  size_t off = 0;
  auto alloc = [&](size_t bytes) -> char* {
    char* p = ws + off;
    off = (off + bytes + 255) & ~(size_t)255;
    return p;
  };
  u16*   w1bf    = (u16*)alloc(512ull * 5632 * 2);
  u16*   w2bf    = (u16*)alloc(384ull * 512 * 2);
  float* bnS     = (float*)alloc(512 * 4);
  float* bnT     = (float*)alloc(512 * 4);
  float* border2 = (float*)alloc(384 * 4);
  u16*   h       = (u16*)alloc(16384ull * 512 * 2);
  float* c2      = (float*)alloc(16384ull * 384 * 4);

  const size_t XT  = 16384ull * 5632 * 2;        // 184.5 MB
  const size_t PB2 = 2 * 16384ull * 512 * 4;     // 134.2 MB

  k_params<<<dim3(1), dim3(512), 0, stream>>>(gamma, beta, mean, var, bnS, bnT);
  k_convert<<<dim3(2816), dim3(256), 0, stream>>>(w1, w1bf, 512 * 5632 / 4);
  k_convert<<<dim3(192), dim3(256), 0, stream>>>(w2, w2bf, 384 * 512 / 4);
  k_border2<<<dim3(384), dim3(64), 0, stream>>>(w2, b2, bnT, border2);

  if (off + XT + PB2 + 4096 <= ws_size) {
    // Tier 1: full transpose + K-split GEMM (grid 1024) + combine
    u16*   xT = (u16*)alloc(XT);
    float* P  = (float*)alloc(PB2);
    k_trans<<<dim3(16 * 88 * 16), dim3(256), 0, stream>>>(x, xT, 0, 16);
    k_gemm1t<1><<<dim3(1024), dim3(256), 0, stream>>>(xT, w1bf, bnS, bnT, h, P, 0, 128);
    k_combine<<<dim3(8192), dim3(256), 0, stream>>>(P, bnS, bnT, h);
  } else if (off + XT + 4096 <= ws_size) {
    // Tier 2: full transpose + single full-K GEMM (grid 512)
    u16* xT = (u16*)alloc(XT);
    k_trans<<<dim3(16 * 88 * 16), dim3(256), 0, stream>>>(x, xT, 0, 16);
    k_gemm1t<0><<<dim3(512), dim3(256), 0, stream>>>(xT, w1bf, bnS, bnT, h, nullptr, 0, 128);
  } else {
    // Tier 3: chunked transpose+GEMM
    int nc = 2;
    while (nc < 16 && off + XT / nc + 4096 > ws_size) nc <<= 1;
    int CB = 16 / nc;
    u16* xT = (u16*)alloc(XT / nc);
    for (int c = 0; c < nc; ++c) {
      k_trans<<<dim3(CB * 88 * 16), dim3(256), 0, stream>>>(x, xT, c * CB, CB);
      k_gemm1t<0><<<dim3(CB * 8 * 4), dim3(256), 0, stream>>>(
          xT, w1bf, bnS, bnT, h, nullptr, c * CB * 1024, CB * 8);
    }
  }
  k_gemm2<<<dim3(128 * 3), dim3(256), 0, stream>>>(h, w2bf, b2, c2);
  k_out<<<dim3(16 * 256), dim3(256), 0, stream>>>(c2, border2, out);
}